// Round 10
// baseline (291.692 us; speedup 1.0000x reference)
//
#include <hip/hip_runtime.h>
#include <hip/hip_bf16.h>
#include <math.h>

#define N_TOK 4096
#define DIM 512
#define IDIM 2048
#define NEXP 8

// bf16 weight conversion geometry (elements)
#define W1_ELS 8388608   // 8*2048*512
#define W3_ELS 8388608
#define W2_ELS 8388608
#define SW1_ELS 1048576
#define SW2_ELS 1048576
#define CONV_ELS 27262976
#define CONV_CHUNKS 3407872   // CONV_ELS/8
#define GATE_BLOCKS 256
#define CONV_BLOCKS 2048
#define CONV_THREADS (CONV_BLOCKS * 256)

typedef __attribute__((ext_vector_type(8))) short bf16x8;
typedef __attribute__((ext_vector_type(4))) float floatx4;

__device__ __forceinline__ short f2bf(float f) {
  unsigned int u;
  __builtin_memcpy(&u, &f, 4);
  u += 0x7fff + ((u >> 16) & 1);  // round-to-nearest-even
  return (short)(u >> 16);
}

__device__ __forceinline__ bf16x8 ld8f(const float* __restrict__ p) {
  float4 a = *(const float4*)p;
  float4 b = *(const float4*)(p + 4);
  bf16x8 v;
  v[0] = f2bf(a.x); v[1] = f2bf(a.y); v[2] = f2bf(a.z); v[3] = f2bf(a.w);
  v[4] = f2bf(b.x); v[5] = f2bf(b.y); v[6] = f2bf(b.z); v[7] = f2bf(b.w);
  return v;
}

// cheap exact-enough erf: Abramowitz-Stegun 7.1.26, |err| <= 1.5e-7
__device__ __forceinline__ float gelu_exactish(float v) {
  float z = fabsf(v) * 0.70710678118f;
  float tt = 1.f / (1.f + 0.3275911f * z);
  float poly = tt * (0.254829592f + tt * (-0.284496736f + tt * (1.421413741f +
               tt * (-1.453152027f + tt * 1.061405429f))));
  float er = 1.f - poly * __expf(-z * z);
  er = (v < 0.f) ? -er : er;
  return 0.5f * v * (1.f + er);
}

// async global->LDS DMA, 16B/lane, LDS dest = wave-uniform base + lane*16
__device__ __forceinline__ void gll(const short* g, short* l) {
  __builtin_amdgcn_global_load_lds(
      (const __attribute__((address_space(1))) void*)g,
      (__attribute__((address_space(3))) void*)l, 16, 0, 0);
}

// ---- gate (0..255) + fp32->bf16 weight convert (256..2303) -----------------
// NOTE (R6/R7): do NOT fuse the scan in via grid-sync or last-block-done.
// Cooperative launch at capacity was rejected (kernel never ran, R6);
// per-block __threadfence() = device-scope L2 writeback, 2304 of them
// serialized the kernel to 341 us (R7). Kernel-boundary flushes are free.
__global__ __launch_bounds__(256) void gate_conv_kernel(
    const float* __restrict__ x, const float* __restrict__ gw,
    short* __restrict__ xb, int* __restrict__ expert_id,
    const float* __restrict__ w1, const float* __restrict__ w3,
    const float* __restrict__ w2, const float* __restrict__ sw1,
    const float* __restrict__ sw2,
    short* __restrict__ w1b, short* __restrict__ w3b, short* __restrict__ w2b,
    short* __restrict__ sw1b, short* __restrict__ sw2b) {
  __shared__ float xs[16 * 516];   // 16 tokens, padded stride
  __shared__ double ps[16][8][2];
  int t = threadIdx.x;

  if (blockIdx.x >= GATE_BLOCKS) {
    // grid-stride bf16 conversion over the concatenated weight arrays
    long tidg = (long)(blockIdx.x - GATE_BLOCKS) * 256 + t;
    for (long c = tidg; c < CONV_CHUNKS; c += CONV_THREADS) {
      long i = c * 8;
      const float* src;
      short* dst;
      long off;
      if (i < W1_ELS)                          { src = w1;  dst = w1b;  off = i; }
      else if (i < 2L * W1_ELS)                { src = w3;  dst = w3b;  off = i - W1_ELS; }
      else if (i < 3L * W1_ELS)                { src = w2;  dst = w2b;  off = i - 2L * W1_ELS; }
      else if (i < 3L * W1_ELS + SW1_ELS)      { src = sw1; dst = sw1b; off = i - 3L * W1_ELS; }
      else                                     { src = sw2; dst = sw2b; off = i - 3L * W1_ELS - SW1_ELS; }
      *(bf16x8*)(dst + off) = ld8f(src + off);
    }
    return;
  }

  int tok0 = blockIdx.x * 16;
  const float* xrow = x + (long)tok0 * DIM;
  for (int i = t; i < 2048; i += 256) {  // i indexes float4
    float4 v = ((const float4*)xrow)[i];
    int row = i >> 7, c4 = i & 127;
    *(float4*)&xs[row * 516 + c4 * 4] = v;
    short4 b;
    b.x = f2bf(v.x); b.y = f2bf(v.y); b.z = f2bf(v.z); b.w = f2bf(v.w);
    *(short4*)(xb + (long)tok0 * DIM + i * 4) = b;
  }
  __syncthreads();
  int tok = t & 15, e = (t >> 4) & 7, hf = t >> 7;
  const float* xr = &xs[tok * 516 + hf * 256];
  const float* wr = gw + e * DIM + hf * 256;
  double s = 0.0;
  for (int k = 0; k < 256; k += 4) {
    float4 xv = *(const float4*)(xr + k);
    float4 wv = *(const float4*)(wr + k);
    s += (double)xv.x * wv.x + (double)xv.y * wv.y +
         (double)xv.z * wv.z + (double)xv.w * wv.w;
  }
  ps[tok][e][hf] = s;
  __syncthreads();
  if (t < 16) {
    double best = ps[t][0][0] + ps[t][0][1];
    int bi = 0;
#pragma unroll
    for (int j = 1; j < 8; j++) {  // strict > keeps lowest index on ties
      double v = ps[t][j][0] + ps[t][j][1];
      if (v > best) { best = v; bi = j; }
    }
    expert_id[tok0 + t] = bi;
  }
}

// ---- scan: histogram + offsets + tile tables + perm scatter (1 block) ------
// Scatter cursors live in LDS (R5: global atomicAdd on 8 addrs was ~50 us).
__global__ __launch_bounds__(256) void scan_scatter(
    const int* __restrict__ expert_id, int* __restrict__ counts,
    int* __restrict__ offsets, int* __restrict__ cursors, int* __restrict__ nmeta,
    int* __restrict__ te1, int* __restrict__ tr1,
    int* __restrict__ te2, int* __restrict__ tr2, int* __restrict__ perm) {
  __shared__ int cnt[8];
  __shared__ int scur[8];
  int tid = threadIdx.x;
  if (tid < 8) cnt[tid] = 0;
  __syncthreads();
  int eid[16];
#pragma unroll
  for (int j = 0; j < 16; j++) {
    eid[j] = expert_id[tid + j * 256];
    atomicAdd(&cnt[eid[j]], 1);
  }
  __syncthreads();
  if (tid == 0) {
    int acc = 0;
    for (int e = 0; e < NEXP; e++) {
      counts[e] = cnt[e];
      offsets[e] = acc;
      scur[e] = acc;
      acc += cnt[e];
    }
    int n1 = 0;
    for (int e = 0; e < NEXP; e++)
      for (int r = 0; r < cnt[e]; r += 128) { te1[n1] = e; tr1[n1] = r; n1++; }
    for (int r = 0; r < N_TOK; r += 128) { te1[n1] = 8; tr1[n1] = r; n1++; }
    int n2 = 0;
    for (int e = 0; e < NEXP; e++)
      for (int r = 0; r < cnt[e]; r += 64) { te2[n2] = e; tr2[n2] = r; n2++; }
    nmeta[0] = n1;  // <= 71
    nmeta[1] = n2;  // <= 71
  }
  __syncthreads();
#pragma unroll
  for (int j = 0; j < 16; j++) {
    int slot = atomicAdd(&scur[eid[j]], 1);   // LDS atomic: ~cycles, no L2 RMW
    perm[slot] = tid + j * 256;
  }
}

// ---- stage1: h = silu(Xe@w1^T)*(Xe@w3^T); g = gelu(Xs@sw1^T), sorted rows --
// BM=128 BN=64 dual-B BK=64. R9: T14 async-STAGE pipeline — B1/B2 gll
// double-buffered (32KB), A staged global->reg->LDS (prefetch int4x4 issued
// BEFORE the MFMA phase, ds_write after the post-MFMA barrier). Both barrier
// drains now land after the compute that hides them. 48KB LDS, 3 blocks/CU,
// (256,3) => reg cap ~170 (uses ~150, no spill — R2 spill lesson).
__global__ __launch_bounds__(256, 3) void stage1(
    const short* __restrict__ xb, const short* __restrict__ w1b,
    const short* __restrict__ w3b, const short* __restrict__ sw1b,
    short* __restrict__ h, short* __restrict__ g,
    const int* __restrict__ counts, const int* __restrict__ offsets,
    const int* __restrict__ nmeta, const int* __restrict__ te,
    const int* __restrict__ tr, const int* __restrict__ perm) {
  __shared__ short Al[128 * 64];       // 16KB, single (reg-staged)
  __shared__ short B1l[2][64 * 64];    // 16KB, gll dbuf
  __shared__ short B2l[2][64 * 64];    // 16KB, gll dbuf
  int t = blockIdx.y;
  if (t >= nmeta[0]) return;
  int e = te[t], row0 = tr[t];
  bool routed = (e < 8);
  int cnt = routed ? counts[e] : N_TOK;
  int base = routed ? offsets[e] : 0;
  int n0 = blockIdx.x * 64;
  int tid = threadIdx.x, lane = tid & 63, w = tid >> 6;
  int wm = w >> 1, wn = w & 1;
  const short* B1 = routed ? w1b + (long)e * IDIM * DIM : sw1b;
  const short* B2 = w3b + (long)e * IDIM * DIM;  // never loaded if !routed

  // A: 1024 chunks of 8 bf16, 4/thread, klog-swizzle in global addr
  int aoff[4], lbA[4];
#pragma unroll
  for (int j = 0; j < 4; j++) {
    int c = w * 256 + j * 64 + lane;
    int row = c >> 3, klog = (c & 7) ^ (row & 7);
    int srow = row0 + row;
    int slot = base + ((srow < cnt) ? srow : (cnt - 1));
    aoff[j] = perm[slot] * DIM + klog * 8;
    lbA[j] = (w * 256 + j * 64) * 8;  // wave-uniform base (shorts)
  }
  // B: 512 chunks of 8 bf16 per matrix, 2 gll/thread, same klog swizzle
  int bgoff[2], lbB[2];
#pragma unroll
  for (int i = 0; i < 2; i++) {
    int c = i * 256 + tid;
    int row = c >> 3, klog = (c & 7) ^ (row & 7);
    bgoff[i] = (n0 + row) * DIM + klog * 8;  // bf16 elements
    lbB[i] = (i * 256 + w * 64) * 8;         // wave-uniform base (shorts)
  }

  floatx4 acc[2][4][2];
#pragma unroll
  for (int m = 0; m < 2; m++)
#pragma unroll
    for (int i = 0; i < 4; i++)
#pragma unroll
      for (int j = 0; j < 2; j++) acc[m][i][j] = (floatx4)0.f;

  // ---- prologue: stage k=0 ----
  int4 areg[4];
#pragma unroll
  for (int j = 0; j < 4; j++)
    areg[j] = *(const int4*)(xb + aoff[j]);
#pragma unroll
  for (int i = 0; i < 2; i++) gll(B1 + bgoff[i], &B1l[0][lbB[i]]);
  if (routed) {
#pragma unroll
    for (int i = 0; i < 2; i++) gll(B2 + bgoff[i], &B2l[0][lbB[i]]);
  }
#pragma unroll
  for (int j = 0; j < 4; j++)
    *(int4*)&Al[lbA[j] + lane * 8] = areg[j];
  __syncthreads();   // drains vmcnt (gll) + lgkm (ds_write)

  for (int kc = 0; kc < DIM; kc += 64) {
    int b = (kc >> 6) & 1;
    bool pf = (kc + 64 < DIM);
    // issue next K-step's loads BEFORE compute (latency hides under MFMA)
    if (pf) {
#pragma unroll
      for (int j = 0; j < 4; j++)
        areg[j] = *(const int4*)(xb + aoff[j] + kc + 64);
#pragma unroll
      for (int i = 0; i < 2; i++)
        gll(B1 + bgoff[i] + kc + 64, &B1l[b ^ 1][lbB[i]]);
      if (routed) {
#pragma unroll
        for (int i = 0; i < 2; i++)
          gll(B2 + bgoff[i] + kc + 64, &B2l[b ^ 1][lbB[i]]);
      }
    }

#pragma unroll
    for (int kf = 0; kf < 2; kf++) {
      int kp = (kf * 4 + (lane >> 4)) ^ (lane & 7);
      bf16x8 af[4];
#pragma unroll
      for (int mf = 0; mf < 4; mf++) {
        int row = wm * 64 + mf * 16 + (lane & 15);
        af[mf] = *(const bf16x8*)&Al[row * 64 + kp * 8];
      }
#pragma unroll
      for (int nf = 0; nf < 2; nf++) {
        int col = wn * 32 + nf * 16 + (lane & 15);
        bf16x8 b1 = *(const bf16x8*)&B1l[b][col * 64 + kp * 8];
#pragma unroll
        for (int mf = 0; mf < 4; mf++)
          acc[0][mf][nf] = __builtin_amdgcn_mfma_f32_16x16x32_bf16(
              af[mf], b1, acc[0][mf][nf], 0, 0, 0);
        if (routed) {
          bf16x8 b2 = *(const bf16x8*)&B2l[b][col * 64 + kp * 8];
#pragma unroll
          for (int mf = 0; mf < 4; mf++)
            acc[1][mf][nf] = __builtin_amdgcn_mfma_f32_16x16x32_bf16(
                af[mf], b2, acc[1][mf][nf], 0, 0, 0);
        }
      }
    }
    __syncthreads();   // all waves done reading Al/B[b]; prefetch landed
    if (pf) {
#pragma unroll
      for (int j = 0; j < 4; j++)
        *(int4*)&Al[lbA[j] + lane * 8] = areg[j];
    }
    __syncthreads();   // Al(k+1) visible
  }

  // epilogue: activate -> LDS stage (quad-XOR col swizzle) -> coalesced store
  // C/D mapping: col = lane&15, row = quad*4 + reg
  short* S = Al;  // 128x64 shorts = 16KB, loop-trailing barrier protects reuse
  int quad = lane >> 4;
  short* dst = routed ? h : g;
#pragma unroll
  for (int mf = 0; mf < 4; mf++)
#pragma unroll
    for (int r = 0; r < 4; r++) {
      int lr = wm * 64 + mf * 16 + quad * 4 + r;     // local row 0..127
      int sw = ((lr >> 2) & 3) << 4;
#pragma unroll
      for (int nf = 0; nf < 2; nf++) {
        int lc = wn * 32 + nf * 16 + (lane & 15);
        float a1 = acc[0][mf][nf][r];
        short v;
        if (routed) {
          float a3 = acc[1][mf][nf][r];
          v = f2bf((a1 / (1.f + __expf(-a1))) * a3);
        } else {
          v = f2bf(gelu_exactish(a1));
        }
        S[lr * 64 + ((lc & 48) ^ sw) + (lc & 15)] = v;
      }
    }
  __syncthreads();
#pragma unroll
  for (int pass = 0; pass < 2; pass++) {
    int lr = pass * 64 + (tid >> 2);
    int srow = row0 + lr;
    if (srow < cnt) {
      int p = (tid & 3) * 16;                        // 16-col chunk base
      int lcs = p ^ (((lr >> 2) & 3) << 4);
      bf16x8 v0 = *(const bf16x8*)&S[lr * 64 + lcs];
      bf16x8 v1 = *(const bf16x8*)&S[lr * 64 + lcs + 8];
      long ro = (long)(base + srow) * IDIM + n0 + p;
      *(bf16x8*)&dst[ro] = v0;
      *(bf16x8*)&dst[ro + 8] = v1;
    }
  }
}

// ---- stage2: out[perm[rows]] = He@w2^T + Ge@sw2^T, fused, no atomics. -----
// BM=64 BN=32 BK=64 bf16 gll (R5-exact; R8's BK=128 regressed +8.5us —
// barrier count is NOT stage2's limiter). h and g are BOTH in sorted row
// order, so one block sums both GEMMs and stores out exactly once.
// N-split (16 n-tiles) gives 1152 blocks; 12KB LDS -> 8 blocks/CU.
// Bijective XCD chunk-swizzle (1152 = 8 x 144).
__global__ __launch_bounds__(256, 8) void stage2(
    const short* __restrict__ h, const short* __restrict__ g,
    const short* __restrict__ w2b, const short* __restrict__ sw2b,
    float* __restrict__ out, const int* __restrict__ counts,
    const int* __restrict__ offsets, const int* __restrict__ nmeta,
    const int* __restrict__ te, const int* __restrict__ tr,
    const int* __restrict__ perm) {
  __shared__ short Al[64 * 64];   // 8KB
  __shared__ short Bl[32 * 64];   // 4KB
  int lid = blockIdx.x + 16 * blockIdx.y;
  int logical = (lid & 7) * 144 + (lid >> 3);
  int t = logical >> 4;
  int n0 = (logical & 15) * 32;
  if (t >= nmeta[1]) return;
  int e = te[t], row0 = tr[t];
  int cnt = counts[e], base = offsets[e];
  const short* w2e = w2b + (long)e * DIM * IDIM;
  int tid = threadIdx.x, lane = tid & 63, w = tid >> 6;
  int wm = w >> 1, wn = w & 1;

  // A: 64x64 = 512 chunks of 8 bf16, 2 gll/thread
  int aoff[2], lbA[2];
#pragma unroll
  for (int i = 0; i < 2; i++) {
    int c = i * 256 + tid;
    int row = c >> 3, klog = (c & 7) ^ (row & 7);
    int srow = row0 + row;
    int arow = base + ((srow < cnt) ? srow : (cnt - 1));
    aoff[i] = arow * IDIM + klog * 8;
    lbA[i] = (i * 256 + w * 64) * 8;  // wave-uniform base
  }
  // B: 32x64 = 256 chunks, 1 gll/thread
  int brow = tid >> 3, bklog = (tid & 7) ^ (brow & 7);
  int bgoff = (n0 + brow) * IDIM + bklog * 8;
  int lbB = (w * 64) * 8;             // wave-uniform base

  floatx4 acc[2];
  acc[0] = (floatx4)0.f;
  acc[1] = (floatx4)0.f;

#pragma unroll
  for (int ph = 0; ph < 2; ph++) {
    const short* As = ph ? g : h;
    const short* Bs = ph ? sw2b : w2e;
    for (int kc = 0; kc < IDIM; kc += 64) {
#pragma unroll
      for (int i = 0; i < 2; i++) gll(As + aoff[i] + kc, &Al[lbA[i]]);
      gll(Bs + bgoff + kc, &Bl[lbB]);
      __syncthreads();

#pragma unroll
      for (int kf = 0; kf < 2; kf++) {
        int kp = (kf * 4 + (lane >> 4)) ^ (lane & 7);
        int col = wn * 16 + (lane & 15);
        bf16x8 bv = *(const bf16x8*)&Bl[col * 64 + kp * 8];
#pragma unroll
        for (int mf = 0; mf < 2; mf++) {
          int row = wm * 32 + mf * 16 + (lane & 15);
          bf16x8 af = *(const bf16x8*)&Al[row * 64 + kp * 8];
          acc[mf] = __builtin_amdgcn_mfma_f32_16x16x32_bf16(
              af, bv, acc[mf], 0, 0, 0);
        }
      }
      __syncthreads();
    }
  }

  int quad = lane >> 4;
  int colb = n0 + wn * 16 + (lane & 15);
#pragma unroll
  for (int mf = 0; mf < 2; mf++)
#pragma unroll
    for (int r = 0; r < 4; r++) {
      int srow = row0 + wm * 32 + mf * 16 + quad * 4 + r;
      if (srow >= cnt) continue;
      long ro = (long)perm[base + srow] * DIM + colb;
      out[ro] = acc[mf][r];
    }
}

extern "C" void kernel_launch(void* const* d_in, const int* in_sizes, int n_in,
                              void* d_out, int out_size, void* d_ws, size_t ws_size,
                              hipStream_t stream) {
  const float* x = (const float*)d_in[0];
  const float* gate_w = (const float*)d_in[1];
  const float* w1 = (const float*)d_in[2];
  const float* w2 = (const float*)d_in[3];
  const float* w3 = (const float*)d_in[4];
  const float* sw1 = (const float*)d_in[5];
  const float* sw2 = (const float*)d_in[6];
  float* out = (float*)d_out;

  char* ws = (char*)d_ws;
  int* counts = (int*)ws;          // 8
  int* offsets = counts + 8;       // 8
  int* cursors = offsets + 8;      // 8 (unused; layout kept)
  int* nmeta = cursors + 8;        // 8
  int* te1 = nmeta + 8;            // 128
  int* tr1 = te1 + 128;            // 128
  int* te2 = tr1 + 128;            // 128
  int* tr2 = te2 + 128;            // 128
  int* expert_id = tr2 + 128;      // 4096
  int* perm = expert_id + N_TOK;   // 4096
  short* xb = (short*)(ws + 65536);        // 4 MB   [N_TOK, DIM] bf16
  short* h = xb + (size_t)N_TOK * DIM;     // 16 MB  [N_TOK, IDIM] sorted rows
  short* g = h + (size_t)N_TOK * IDIM;     // 16 MB  [N_TOK, IDIM] sorted rows
  short* w1b = g + (size_t)N_TOK * IDIM;   // 16 MB  bf16 weights from here
  short* w3b = w1b + (size_t)W1_ELS;       // 16 MB
  short* w2b = w3b + (size_t)W3_ELS;       // 16 MB
  short* sw1b = w2b + (size_t)W2_ELS;      // 2 MB
  short* sw2b = sw1b + (size_t)SW1_ELS;    // 2 MB   total ws ~= 92.4 MB

  gate_conv_kernel<<<GATE_BLOCKS + CONV_BLOCKS, 256, 0, stream>>>(
      x, gate_w, xb, expert_id, w1, w3, w2, sw1, sw2,
      w1b, w3b, w2b, sw1b, sw2b);
  scan_scatter<<<1, 256, 0, stream>>>(expert_id, counts, offsets, cursors, nmeta,
                                      te1, tr1, te2, tr2, perm);
  stage1<<<dim3(IDIM / 64, 72), 256, 0, stream>>>(
      xb, w1b, w3b, sw1b, h, g, counts, offsets, nmeta, te1, tr1, perm);
  stage2<<<dim3(16, 72), 256, 0, stream>>>(
      h, g, w2b, sw2b, out, counts, offsets, nmeta, te2, tr2, perm);
}

// Round 11
// 242.458 us; speedup vs baseline: 1.2031x; 1.2031x over previous
//
#include <hip/hip_runtime.h>
#include <hip/hip_bf16.h>
#include <math.h>

#define N_TOK 4096
#define DIM 512
#define IDIM 2048
#define NEXP 8

// bf16 weight conversion geometry (elements)
#define W1_ELS 8388608   // 8*2048*512
#define W3_ELS 8388608
#define W2_ELS 8388608
#define SW1_ELS 1048576
#define SW2_ELS 1048576
#define CONV_ELS 27262976
#define CONV_CHUNKS 3407872   // CONV_ELS/8
#define GATE_BLOCKS 256
#define CONV_BLOCKS 2048
#define CONV_THREADS (CONV_BLOCKS * 256)

typedef __attribute__((ext_vector_type(8))) short bf16x8;
typedef __attribute__((ext_vector_type(4))) float floatx4;

__device__ __forceinline__ short f2bf(float f) {
  unsigned int u;
  __builtin_memcpy(&u, &f, 4);
  u += 0x7fff + ((u >> 16) & 1);  // round-to-nearest-even
  return (short)(u >> 16);
}

__device__ __forceinline__ bf16x8 ld8f(const float* __restrict__ p) {
  float4 a = *(const float4*)p;
  float4 b = *(const float4*)(p + 4);
  bf16x8 v;
  v[0] = f2bf(a.x); v[1] = f2bf(a.y); v[2] = f2bf(a.z); v[3] = f2bf(a.w);
  v[4] = f2bf(b.x); v[5] = f2bf(b.y); v[6] = f2bf(b.z); v[7] = f2bf(b.w);
  return v;
}

// cheap exact-enough erf: Abramowitz-Stegun 7.1.26, |err| <= 1.5e-7
__device__ __forceinline__ float gelu_exactish(float v) {
  float z = fabsf(v) * 0.70710678118f;
  float tt = 1.f / (1.f + 0.3275911f * z);
  float poly = tt * (0.254829592f + tt * (-0.284496736f + tt * (1.421413741f +
               tt * (-1.453152027f + tt * 1.061405429f))));
  float er = 1.f - poly * __expf(-z * z);
  er = (v < 0.f) ? -er : er;
  return 0.5f * v * (1.f + er);
}

// async global->LDS DMA, 16B/lane, LDS dest = wave-uniform base + lane*16
__device__ __forceinline__ void gll(const short* g, short* l) {
  __builtin_amdgcn_global_load_lds(
      (const __attribute__((address_space(1))) void*)g,
      (__attribute__((address_space(3))) void*)l, 16, 0, 0);
}

// ---- gate (0..255) + fp32->bf16 weight convert (256..2303) -----------------
// NOTE (R6/R7): do NOT fuse the scan in via grid-sync or last-block-done.
// Cooperative launch at capacity was rejected (kernel never ran, R6);
// per-block __threadfence() = device-scope L2 writeback, 2304 of them
// serialized the kernel to 341 us (R7). Kernel-boundary flushes are free.
__global__ __launch_bounds__(256) void gate_conv_kernel(
    const float* __restrict__ x, const float* __restrict__ gw,
    short* __restrict__ xb, int* __restrict__ expert_id,
    const float* __restrict__ w1, const float* __restrict__ w3,
    const float* __restrict__ w2, const float* __restrict__ sw1,
    const float* __restrict__ sw2,
    short* __restrict__ w1b, short* __restrict__ w3b, short* __restrict__ w2b,
    short* __restrict__ sw1b, short* __restrict__ sw2b) {
  __shared__ float xs[16 * 516];   // 16 tokens, padded stride
  __shared__ double ps[16][8][2];
  int t = threadIdx.x;

  if (blockIdx.x >= GATE_BLOCKS) {
    // grid-stride bf16 conversion over the concatenated weight arrays
    long tidg = (long)(blockIdx.x - GATE_BLOCKS) * 256 + t;
    for (long c = tidg; c < CONV_CHUNKS; c += CONV_THREADS) {
      long i = c * 8;
      const float* src;
      short* dst;
      long off;
      if (i < W1_ELS)                          { src = w1;  dst = w1b;  off = i; }
      else if (i < 2L * W1_ELS)                { src = w3;  dst = w3b;  off = i - W1_ELS; }
      else if (i < 3L * W1_ELS)                { src = w2;  dst = w2b;  off = i - 2L * W1_ELS; }
      else if (i < 3L * W1_ELS + SW1_ELS)      { src = sw1; dst = sw1b; off = i - 3L * W1_ELS; }
      else                                     { src = sw2; dst = sw2b; off = i - 3L * W1_ELS - SW1_ELS; }
      *(bf16x8*)(dst + off) = ld8f(src + off);
    }
    return;
  }

  int tok0 = blockIdx.x * 16;
  const float* xrow = x + (long)tok0 * DIM;
  for (int i = t; i < 2048; i += 256) {  // i indexes float4
    float4 v = ((const float4*)xrow)[i];
    int row = i >> 7, c4 = i & 127;
    *(float4*)&xs[row * 516 + c4 * 4] = v;
    short4 b;
    b.x = f2bf(v.x); b.y = f2bf(v.y); b.z = f2bf(v.z); b.w = f2bf(v.w);
    *(short4*)(xb + (long)tok0 * DIM + i * 4) = b;
  }
  __syncthreads();
  int tok = t & 15, e = (t >> 4) & 7, hf = t >> 7;
  const float* xr = &xs[tok * 516 + hf * 256];
  const float* wr = gw + e * DIM + hf * 256;
  double s = 0.0;
  for (int k = 0; k < 256; k += 4) {
    float4 xv = *(const float4*)(xr + k);
    float4 wv = *(const float4*)(wr + k);
    s += (double)xv.x * wv.x + (double)xv.y * wv.y +
         (double)xv.z * wv.z + (double)xv.w * wv.w;
  }
  ps[tok][e][hf] = s;
  __syncthreads();
  if (t < 16) {
    double best = ps[t][0][0] + ps[t][0][1];
    int bi = 0;
#pragma unroll
    for (int j = 1; j < 8; j++) {  // strict > keeps lowest index on ties
      double v = ps[t][j][0] + ps[t][j][1];
      if (v > best) { best = v; bi = j; }
    }
    expert_id[tok0 + t] = bi;
  }
}

// ---- scan: histogram + offsets + tile tables + perm scatter (1 block) ------
// Scatter cursors live in LDS (R5: global atomicAdd on 8 addrs was ~50 us).
__global__ __launch_bounds__(256) void scan_scatter(
    const int* __restrict__ expert_id, int* __restrict__ counts,
    int* __restrict__ offsets, int* __restrict__ cursors, int* __restrict__ nmeta,
    int* __restrict__ te1, int* __restrict__ tr1,
    int* __restrict__ te2, int* __restrict__ tr2, int* __restrict__ perm) {
  __shared__ int cnt[8];
  __shared__ int scur[8];
  int tid = threadIdx.x;
  if (tid < 8) cnt[tid] = 0;
  __syncthreads();
  int eid[16];
#pragma unroll
  for (int j = 0; j < 16; j++) {
    eid[j] = expert_id[tid + j * 256];
    atomicAdd(&cnt[eid[j]], 1);
  }
  __syncthreads();
  if (tid == 0) {
    int acc = 0;
    for (int e = 0; e < NEXP; e++) {
      counts[e] = cnt[e];
      offsets[e] = acc;
      scur[e] = acc;
      acc += cnt[e];
    }
    int n1 = 0;
    for (int e = 0; e < NEXP; e++)
      for (int r = 0; r < cnt[e]; r += 128) { te1[n1] = e; tr1[n1] = r; n1++; }
    for (int r = 0; r < N_TOK; r += 128) { te1[n1] = 8; tr1[n1] = r; n1++; }
    int n2 = 0;
    for (int e = 0; e < NEXP; e++)
      for (int r = 0; r < cnt[e]; r += 64) { te2[n2] = e; tr2[n2] = r; n2++; }
    nmeta[0] = n1;  // <= 71
    nmeta[1] = n2;  // <= 71
  }
  __syncthreads();
#pragma unroll
  for (int j = 0; j < 16; j++) {
    int slot = atomicAdd(&scur[eid[j]], 1);   // LDS atomic: ~cycles, no L2 RMW
    perm[slot] = tid + j * 256;
  }
}

// ---- stage1: h = silu(Xe@w1^T)*(Xe@w3^T); g = gelu(Xs@sw1^T), sorted rows --
// BM=128 BN=64 dual-B BK=64, all-bf16 gll, single-buffer 2-barrier loop
// (R5-exact structure — three pipelining attempts all regressed:
//  R8 stage2 BK=128 +8.5us; R9/R10 A-reg-staging spilled areg across the
//  MFMA phase, WRITE 35->136MB, 50->104us. The 2-barrier gll ceiling is
//  structural at HIP level; do not re-attempt without the full 8-phase
//  counted-vmcnt template). 32KB LDS, (256,4) load-bearing (R2 spill).
// R11: bijective XCD chunk-swizzle (2304 = 8 x 288): co-locates the 32
// same-A-panel n-tiles and ~9 adjacent t-panels (same-expert B reuse) on
// one XCD's L2 (T1).
__global__ __launch_bounds__(256, 4) void stage1(
    const short* __restrict__ xb, const short* __restrict__ w1b,
    const short* __restrict__ w3b, const short* __restrict__ sw1b,
    short* __restrict__ h, short* __restrict__ g,
    const int* __restrict__ counts, const int* __restrict__ offsets,
    const int* __restrict__ nmeta, const int* __restrict__ te,
    const int* __restrict__ tr, const int* __restrict__ perm) {
  __shared__ short Al[128 * 64];
  __shared__ short B1l[64 * 64];
  __shared__ short B2l[64 * 64];
  int lid = blockIdx.x + 32 * blockIdx.y;   // grid (32, 72) = 2304 blocks
  int logical = (lid & 7) * 288 + (lid >> 3);
  int t = logical >> 5;
  int n0 = (logical & 31) * 64;
  if (t >= nmeta[0]) return;
  int e = te[t], row0 = tr[t];
  bool routed = (e < 8);
  int cnt = routed ? counts[e] : N_TOK;
  int base = routed ? offsets[e] : 0;
  int tid = threadIdx.x, lane = tid & 63, w = tid >> 6;
  int wm = w >> 1, wn = w & 1;
  const short* B1 = routed ? w1b + (long)e * IDIM * DIM : sw1b;
  const short* B2 = w3b + (long)e * IDIM * DIM;  // never loaded if !routed

  // A: 1024 chunks of 8 bf16, 4 gll/thread, klog-swizzle in global addr
  int aoff[4], lbA[4];
#pragma unroll
  for (int j = 0; j < 4; j++) {
    int c = w * 256 + j * 64 + lane;
    int row = c >> 3, klog = (c & 7) ^ (row & 7);
    int srow = row0 + row;
    int slot = base + ((srow < cnt) ? srow : (cnt - 1));
    aoff[j] = perm[slot] * DIM + klog * 8;
    lbA[j] = (w * 256 + j * 64) * 8;  // wave-uniform base (shorts)
  }
  // B: 512 chunks of 8 bf16 per matrix, 2 gll/thread, same klog swizzle
  int bgoff[2], lbB[2];
#pragma unroll
  for (int i = 0; i < 2; i++) {
    int c = i * 256 + tid;
    int row = c >> 3, klog = (c & 7) ^ (row & 7);
    bgoff[i] = (n0 + row) * DIM + klog * 8;  // bf16 elements
    lbB[i] = (i * 256 + w * 64) * 8;         // wave-uniform base (shorts)
  }

  floatx4 acc[2][4][2];
#pragma unroll
  for (int m = 0; m < 2; m++)
#pragma unroll
    for (int i = 0; i < 4; i++)
#pragma unroll
      for (int j = 0; j < 2; j++) acc[m][i][j] = (floatx4)0.f;

  for (int kc = 0; kc < DIM; kc += 64) {
#pragma unroll
    for (int j = 0; j < 4; j++) gll(xb + aoff[j] + kc, &Al[lbA[j]]);
#pragma unroll
    for (int i = 0; i < 2; i++) gll(B1 + bgoff[i] + kc, &B1l[lbB[i]]);
    if (routed) {
#pragma unroll
      for (int i = 0; i < 2; i++) gll(B2 + bgoff[i] + kc, &B2l[lbB[i]]);
    }
    __syncthreads();

#pragma unroll
    for (int kf = 0; kf < 2; kf++) {
      int kp = (kf * 4 + (lane >> 4)) ^ (lane & 7);
      bf16x8 af[4];
#pragma unroll
      for (int mf = 0; mf < 4; mf++) {
        int row = wm * 64 + mf * 16 + (lane & 15);
        af[mf] = *(const bf16x8*)&Al[row * 64 + kp * 8];
      }
#pragma unroll
      for (int nf = 0; nf < 2; nf++) {
        int col = wn * 32 + nf * 16 + (lane & 15);
        bf16x8 b1 = *(const bf16x8*)&B1l[col * 64 + kp * 8];
#pragma unroll
        for (int mf = 0; mf < 4; mf++)
          acc[0][mf][nf] = __builtin_amdgcn_mfma_f32_16x16x32_bf16(
              af[mf], b1, acc[0][mf][nf], 0, 0, 0);
        if (routed) {
          bf16x8 b2 = *(const bf16x8*)&B2l[col * 64 + kp * 8];
#pragma unroll
          for (int mf = 0; mf < 4; mf++)
            acc[1][mf][nf] = __builtin_amdgcn_mfma_f32_16x16x32_bf16(
                af[mf], b2, acc[1][mf][nf], 0, 0, 0);
        }
      }
    }
    __syncthreads();
  }

  // epilogue: activate -> LDS stage (quad-XOR col swizzle) -> coalesced store
  // C/D mapping: col = lane&15, row = quad*4 + reg
  short* S = Al;  // 128x64 shorts = 16KB, loop-trailing barrier protects reuse
  int quad = lane >> 4;
  short* dst = routed ? h : g;
#pragma unroll
  for (int mf = 0; mf < 4; mf++)
#pragma unroll
    for (int r = 0; r < 4; r++) {
      int lr = wm * 64 + mf * 16 + quad * 4 + r;     // local row 0..127
      int sw = ((lr >> 2) & 3) << 4;
#pragma unroll
      for (int nf = 0; nf < 2; nf++) {
        int lc = wn * 32 + nf * 16 + (lane & 15);
        float a1 = acc[0][mf][nf][r];
        short v;
        if (routed) {
          float a3 = acc[1][mf][nf][r];
          v = f2bf((a1 / (1.f + __expf(-a1))) * a3);
        } else {
          v = f2bf(gelu_exactish(a1));
        }
        S[lr * 64 + ((lc & 48) ^ sw) + (lc & 15)] = v;
      }
    }
  __syncthreads();
#pragma unroll
  for (int pass = 0; pass < 2; pass++) {
    int lr = pass * 64 + (tid >> 2);
    int srow = row0 + lr;
    if (srow < cnt) {
      int p = (tid & 3) * 16;                        // 16-col chunk base
      int lcs = p ^ (((lr >> 2) & 3) << 4);
      bf16x8 v0 = *(const bf16x8*)&S[lr * 64 + lcs];
      bf16x8 v1 = *(const bf16x8*)&S[lr * 64 + lcs + 8];
      long ro = (long)(base + srow) * IDIM + n0 + p;
      *(bf16x8*)&dst[ro] = v0;
      *(bf16x8*)&dst[ro + 8] = v1;
    }
  }
}

// ---- stage2: out[perm[rows]] = He@w2^T + Ge@sw2^T, fused, no atomics. -----
// BM=64 BN=32 BK=64 bf16 gll (R5-exact; R8's BK=128 regressed +8.5us —
// barrier count is NOT stage2's limiter). h and g are BOTH in sorted row
// order, so one block sums both GEMMs and stores out exactly once.
// N-split (16 n-tiles) gives 1152 blocks; 12KB LDS -> 8 blocks/CU.
// Bijective XCD chunk-swizzle (1152 = 8 x 144).
__global__ __launch_bounds__(256, 8) void stage2(
    const short* __restrict__ h, const short* __restrict__ g,
    const short* __restrict__ w2b, const short* __restrict__ sw2b,
    float* __restrict__ out, const int* __restrict__ counts,
    const int* __restrict__ offsets, const int* __restrict__ nmeta,
    const int* __restrict__ te, const int* __restrict__ tr,
    const int* __restrict__ perm) {
  __shared__ short Al[64 * 64];   // 8KB
  __shared__ short Bl[32 * 64];   // 4KB
  int lid = blockIdx.x + 16 * blockIdx.y;
  int logical = (lid & 7) * 144 + (lid >> 3);
  int t = logical >> 4;
  int n0 = (logical & 15) * 32;
  if (t >= nmeta[1]) return;
  int e = te[t], row0 = tr[t];
  int cnt = counts[e], base = offsets[e];
  const short* w2e = w2b + (long)e * DIM * IDIM;
  int tid = threadIdx.x, lane = tid & 63, w = tid >> 6;
  int wm = w >> 1, wn = w & 1;

  // A: 64x64 = 512 chunks of 8 bf16, 2 gll/thread
  int aoff[2], lbA[2];
#pragma unroll
  for (int i = 0; i < 2; i++) {
    int c = i * 256 + tid;
    int row = c >> 3, klog = (c & 7) ^ (row & 7);
    int srow = row0 + row;
    int arow = base + ((srow < cnt) ? srow : (cnt - 1));
    aoff[i] = arow * IDIM + klog * 8;
    lbA[i] = (i * 256 + w * 64) * 8;  // wave-uniform base
  }
  // B: 32x64 = 256 chunks, 1 gll/thread
  int brow = tid >> 3, bklog = (tid & 7) ^ (brow & 7);
  int bgoff = (n0 + brow) * IDIM + bklog * 8;
  int lbB = (w * 64) * 8;             // wave-uniform base

  floatx4 acc[2];
  acc[0] = (floatx4)0.f;
  acc[1] = (floatx4)0.f;

#pragma unroll
  for (int ph = 0; ph < 2; ph++) {
    const short* As = ph ? g : h;
    const short* Bs = ph ? sw2b : w2e;
    for (int kc = 0; kc < IDIM; kc += 64) {
#pragma unroll
      for (int i = 0; i < 2; i++) gll(As + aoff[i] + kc, &Al[lbA[i]]);
      gll(Bs + bgoff + kc, &Bl[lbB]);
      __syncthreads();

#pragma unroll
      for (int kf = 0; kf < 2; kf++) {
        int kp = (kf * 4 + (lane >> 4)) ^ (lane & 7);
        int col = wn * 16 + (lane & 15);
        bf16x8 bv = *(const bf16x8*)&Bl[col * 64 + kp * 8];
#pragma unroll
        for (int mf = 0; mf < 2; mf++) {
          int row = wm * 32 + mf * 16 + (lane & 15);
          bf16x8 af = *(const bf16x8*)&Al[row * 64 + kp * 8];
          acc[mf] = __builtin_amdgcn_mfma_f32_16x16x32_bf16(
              af, bv, acc[mf], 0, 0, 0);
        }
      }
      __syncthreads();
    }
  }

  int quad = lane >> 4;
  int colb = n0 + wn * 16 + (lane & 15);
#pragma unroll
  for (int mf = 0; mf < 2; mf++)
#pragma unroll
    for (int r = 0; r < 4; r++) {
      int srow = row0 + wm * 32 + mf * 16 + quad * 4 + r;
      if (srow >= cnt) continue;
      long ro = (long)perm[base + srow] * DIM + colb;
      out[ro] = acc[mf][r];
    }
}

extern "C" void kernel_launch(void* const* d_in, const int* in_sizes, int n_in,
                              void* d_out, int out_size, void* d_ws, size_t ws_size,
                              hipStream_t stream) {
  const float* x = (const float*)d_in[0];
  const float* gate_w = (const float*)d_in[1];
  const float* w1 = (const float*)d_in[2];
  const float* w2 = (const float*)d_in[3];
  const float* w3 = (const float*)d_in[4];
  const float* sw1 = (const float*)d_in[5];
  const float* sw2 = (const float*)d_in[6];
  float* out = (float*)d_out;

  char* ws = (char*)d_ws;
  int* counts = (int*)ws;          // 8
  int* offsets = counts + 8;       // 8
  int* cursors = offsets + 8;      // 8 (unused; layout kept)
  int* nmeta = cursors + 8;        // 8
  int* te1 = nmeta + 8;            // 128
  int* tr1 = te1 + 128;            // 128
  int* te2 = tr1 + 128;            // 128
  int* tr2 = te2 + 128;            // 128
  int* expert_id = tr2 + 128;      // 4096
  int* perm = expert_id + N_TOK;   // 4096
  short* xb = (short*)(ws + 65536);        // 4 MB   [N_TOK, DIM] bf16
  short* h = xb + (size_t)N_TOK * DIM;     // 16 MB  [N_TOK, IDIM] sorted rows
  short* g = h + (size_t)N_TOK * IDIM;     // 16 MB  [N_TOK, IDIM] sorted rows
  short* w1b = g + (size_t)N_TOK * IDIM;   // 16 MB  bf16 weights from here
  short* w3b = w1b + (size_t)W1_ELS;       // 16 MB
  short* w2b = w3b + (size_t)W3_ELS;       // 16 MB
  short* sw1b = w2b + (size_t)W2_ELS;      // 2 MB
  short* sw2b = sw1b + (size_t)SW1_ELS;    // 2 MB   total ws ~= 92.4 MB

  gate_conv_kernel<<<GATE_BLOCKS + CONV_BLOCKS, 256, 0, stream>>>(
      x, gate_w, xb, expert_id, w1, w3, w2, sw1, sw2,
      w1b, w3b, w2b, sw1b, sw2b);
  scan_scatter<<<1, 256, 0, stream>>>(expert_id, counts, offsets, cursors, nmeta,
                                      te1, tr1, te2, tr2, perm);
  stage1<<<dim3(IDIM / 64, 72), 256, 0, stream>>>(
      xb, w1b, w3b, sw1b, h, g, counts, offsets, nmeta, te1, tr1, perm);
  stage2<<<dim3(16, 72), 256, 0, stream>>>(
      h, g, w2b, sw2b, out, counts, offsets, nmeta, te2, tr2, perm);
}

// Round 12
// 242.421 us; speedup vs baseline: 1.2032x; 1.0002x over previous
//
#include <hip/hip_runtime.h>
#include <hip/hip_bf16.h>
#include <math.h>

#define N_TOK 4096
#define DIM 512
#define IDIM 2048
#define NEXP 8

// bf16 weight conversion geometry (elements)
#define W1_ELS 8388608   // 8*2048*512
#define W3_ELS 8388608
#define W2_ELS 8388608
#define SW1_ELS 1048576
#define SW2_ELS 1048576
#define CONV_ELS 27262976
#define CONV_CHUNKS 3407872   // CONV_ELS/8
#define GATE_BLOCKS 256
#define CONV_BLOCKS 2048
#define CONV_THREADS (CONV_BLOCKS * 256)

typedef __attribute__((ext_vector_type(8))) short bf16x8;
typedef __attribute__((ext_vector_type(4))) float floatx4;

__device__ __forceinline__ short f2bf(float f) {
  unsigned int u;
  __builtin_memcpy(&u, &f, 4);
  u += 0x7fff + ((u >> 16) & 1);  // round-to-nearest-even
  return (short)(u >> 16);
}

__device__ __forceinline__ bf16x8 ld8f(const float* __restrict__ p) {
  float4 a = *(const float4*)p;
  float4 b = *(const float4*)(p + 4);
  bf16x8 v;
  v[0] = f2bf(a.x); v[1] = f2bf(a.y); v[2] = f2bf(a.z); v[3] = f2bf(a.w);
  v[4] = f2bf(b.x); v[5] = f2bf(b.y); v[6] = f2bf(b.z); v[7] = f2bf(b.w);
  return v;
}

// cheap exact-enough erf: Abramowitz-Stegun 7.1.26, |err| <= 1.5e-7
__device__ __forceinline__ float gelu_exactish(float v) {
  float z = fabsf(v) * 0.70710678118f;
  float tt = 1.f / (1.f + 0.3275911f * z);
  float poly = tt * (0.254829592f + tt * (-0.284496736f + tt * (1.421413741f +
               tt * (-1.453152027f + tt * 1.061405429f))));
  float er = 1.f - poly * __expf(-z * z);
  er = (v < 0.f) ? -er : er;
  return 0.5f * v * (1.f + er);
}

// async global->LDS DMA, 16B/lane, LDS dest = wave-uniform base + lane*16
__device__ __forceinline__ void gll(const short* g, short* l) {
  __builtin_amdgcn_global_load_lds(
      (const __attribute__((address_space(1))) void*)g,
      (__attribute__((address_space(3))) void*)l, 16, 0, 0);
}

// ---- gate (0..255) + fp32->bf16 weight convert (256..2303) -----------------
// NOTE (R6/R7): do NOT fuse the scan in via grid-sync or last-block-done.
// Cooperative launch at capacity was rejected (kernel never ran, R6);
// per-block __threadfence() = device-scope L2 writeback, 2304 of them
// serialized the kernel to 341 us (R7). Kernel-boundary flushes are free.
__global__ __launch_bounds__(256) void gate_conv_kernel(
    const float* __restrict__ x, const float* __restrict__ gw,
    short* __restrict__ xb, int* __restrict__ expert_id,
    const float* __restrict__ w1, const float* __restrict__ w3,
    const float* __restrict__ w2, const float* __restrict__ sw1,
    const float* __restrict__ sw2,
    short* __restrict__ w1b, short* __restrict__ w3b, short* __restrict__ w2b,
    short* __restrict__ sw1b, short* __restrict__ sw2b) {
  __shared__ float xs[16 * 516];   // 16 tokens, padded stride
  __shared__ double ps[16][8][2];
  int t = threadIdx.x;

  if (blockIdx.x >= GATE_BLOCKS) {
    // grid-stride bf16 conversion over the concatenated weight arrays
    long tidg = (long)(blockIdx.x - GATE_BLOCKS) * 256 + t;
    for (long c = tidg; c < CONV_CHUNKS; c += CONV_THREADS) {
      long i = c * 8;
      const float* src;
      short* dst;
      long off;
      if (i < W1_ELS)                          { src = w1;  dst = w1b;  off = i; }
      else if (i < 2L * W1_ELS)                { src = w3;  dst = w3b;  off = i - W1_ELS; }
      else if (i < 3L * W1_ELS)                { src = w2;  dst = w2b;  off = i - 2L * W1_ELS; }
      else if (i < 3L * W1_ELS + SW1_ELS)      { src = sw1; dst = sw1b; off = i - 3L * W1_ELS; }
      else                                     { src = sw2; dst = sw2b; off = i - 3L * W1_ELS - SW1_ELS; }
      *(bf16x8*)(dst + off) = ld8f(src + off);
    }
    return;
  }

  int tok0 = blockIdx.x * 16;
  const float* xrow = x + (long)tok0 * DIM;
  for (int i = t; i < 2048; i += 256) {  // i indexes float4
    float4 v = ((const float4*)xrow)[i];
    int row = i >> 7, c4 = i & 127;
    *(float4*)&xs[row * 516 + c4 * 4] = v;
    short4 b;
    b.x = f2bf(v.x); b.y = f2bf(v.y); b.z = f2bf(v.z); b.w = f2bf(v.w);
    *(short4*)(xb + (long)tok0 * DIM + i * 4) = b;
  }
  __syncthreads();
  int tok = t & 15, e = (t >> 4) & 7, hf = t >> 7;
  const float* xr = &xs[tok * 516 + hf * 256];
  const float* wr = gw + e * DIM + hf * 256;
  double s = 0.0;
  for (int k = 0; k < 256; k += 4) {
    float4 xv = *(const float4*)(xr + k);
    float4 wv = *(const float4*)(wr + k);
    s += (double)xv.x * wv.x + (double)xv.y * wv.y +
         (double)xv.z * wv.z + (double)xv.w * wv.w;
  }
  ps[tok][e][hf] = s;
  __syncthreads();
  if (t < 16) {
    double best = ps[t][0][0] + ps[t][0][1];
    int bi = 0;
#pragma unroll
    for (int j = 1; j < 8; j++) {  // strict > keeps lowest index on ties
      double v = ps[t][j][0] + ps[t][j][1];
      if (v > best) { best = v; bi = j; }
    }
    expert_id[tok0 + t] = bi;
  }
}

// ---- scan: histogram + offsets + tile tables + perm scatter (1 block) ------
// Scatter cursors live in LDS (R5: global atomicAdd on 8 addrs was ~50 us).
// R12: te1/tr1 tables at stride 64 (stage1 BM=64), up to 135 entries.
__global__ __launch_bounds__(256) void scan_scatter(
    const int* __restrict__ expert_id, int* __restrict__ counts,
    int* __restrict__ offsets, int* __restrict__ cursors, int* __restrict__ nmeta,
    int* __restrict__ te1, int* __restrict__ tr1,
    int* __restrict__ te2, int* __restrict__ tr2, int* __restrict__ perm) {
  __shared__ int cnt[8];
  __shared__ int scur[8];
  int tid = threadIdx.x;
  if (tid < 8) cnt[tid] = 0;
  __syncthreads();
  int eid[16];
#pragma unroll
  for (int j = 0; j < 16; j++) {
    eid[j] = expert_id[tid + j * 256];
    atomicAdd(&cnt[eid[j]], 1);
  }
  __syncthreads();
  if (tid == 0) {
    int acc = 0;
    for (int e = 0; e < NEXP; e++) {
      counts[e] = cnt[e];
      offsets[e] = acc;
      scur[e] = acc;
      acc += cnt[e];
    }
    int n1 = 0;
    for (int e = 0; e < NEXP; e++)
      for (int r = 0; r < cnt[e]; r += 64) { te1[n1] = e; tr1[n1] = r; n1++; }
    for (int r = 0; r < N_TOK; r += 64) { te1[n1] = 8; tr1[n1] = r; n1++; }
    int n2 = 0;
    for (int e = 0; e < NEXP; e++)
      for (int r = 0; r < cnt[e]; r += 64) { te2[n2] = e; tr2[n2] = r; n2++; }
    nmeta[0] = n1;  // <= 135
    nmeta[1] = n2;  // <= 71
  }
  __syncthreads();
#pragma unroll
  for (int j = 0; j < 16; j++) {
    int slot = atomicAdd(&scur[eid[j]], 1);   // LDS atomic: ~cycles, no L2 RMW
    perm[slot] = tid + j * 256;
  }
}

// ---- stage1: h = silu(Xe@w1^T)*(Xe@w3^T); g = gelu(Xs@sw1^T), sorted rows --
// R12: T3 minimum 2-phase pipeline. BM=64 BN=64 BK=64 dual-B, pure-gll
// double-buffer (six DISTINCT __shared__ arrays so alias analysis statically
// proves prefetch-writes disjoint from compute-reads; K-loop fully unrolled
// so buffer parity is compile-time). Per K-iter: issue next-tile gll ->
// MFMA on current -> ONE __syncthreads (its vmcnt(0) drain lands AFTER the
// MFMA that hides it). No registers live across MFMA (R9/R10 spill fixed:
// acc[2][2][2]=32 VGPRs). 48KB LDS -> 3 blocks/CU. Staging/read pattern
// cloned from stage2's proven 64x64 klog scheme.
__global__ __launch_bounds__(256, 3) void stage1(
    const short* __restrict__ xb, const short* __restrict__ w1b,
    const short* __restrict__ w3b, const short* __restrict__ sw1b,
    short* __restrict__ h, short* __restrict__ g,
    const int* __restrict__ counts, const int* __restrict__ offsets,
    const int* __restrict__ nmeta, const int* __restrict__ te,
    const int* __restrict__ tr, const int* __restrict__ perm) {
  __shared__ short Al0[64 * 64];
  __shared__ short Al1[64 * 64];
  __shared__ short B1l0[64 * 64];
  __shared__ short B1l1[64 * 64];
  __shared__ short B2l0[64 * 64];
  __shared__ short B2l1[64 * 64];
  int t = blockIdx.y;
  if (t >= nmeta[0]) return;
  int e = te[t], row0 = tr[t];
  bool routed = (e < 8);
  int cnt = routed ? counts[e] : N_TOK;
  int base = routed ? offsets[e] : 0;
  int n0 = blockIdx.x * 64;
  int tid = threadIdx.x, lane = tid & 63, w = tid >> 6;
  int wm = w >> 1, wn = w & 1;
  const short* B1 = routed ? w1b + (long)e * IDIM * DIM : sw1b;
  const short* B2 = w3b + (long)e * IDIM * DIM;  // never loaded if !routed

  // A: 64x64 = 512 chunks of 8 bf16, 2 gll/thread, klog source swizzle
  int aoff[2], bgoff[2], lb[2];
#pragma unroll
  for (int i = 0; i < 2; i++) {
    int c = i * 256 + tid;
    int row = c >> 3, klog = (c & 7) ^ (row & 7);
    int srow = row0 + row;
    int slot = base + ((srow < cnt) ? srow : (cnt - 1));
    aoff[i] = perm[slot] * DIM + klog * 8;
    bgoff[i] = (n0 + row) * DIM + klog * 8;
    lb[i] = (i * 256 + w * 64) * 8;  // wave-uniform base (shorts)
  }

  floatx4 acc[2][2][2];
#pragma unroll
  for (int m = 0; m < 2; m++)
#pragma unroll
    for (int i = 0; i < 2; i++)
#pragma unroll
      for (int j = 0; j < 2; j++) acc[m][i][j] = (floatx4)0.f;

  // prologue: stage kc=0 into buffer 0
#pragma unroll
  for (int i = 0; i < 2; i++) gll(xb + aoff[i], &Al0[lb[i]]);
#pragma unroll
  for (int i = 0; i < 2; i++) gll(B1 + bgoff[i], &B1l0[lb[i]]);
  if (routed) {
#pragma unroll
    for (int i = 0; i < 2; i++) gll(B2 + bgoff[i], &B2l0[lb[i]]);
  }
  __syncthreads();

#pragma unroll
  for (int ki = 0; ki < 8; ki++) {           // DIM/64 = 8, fully unrolled
    const int kc = ki * 64;
    short* An = (ki & 1) ? Al0 : Al1;        // next buffers (parity ki+1)
    short* B1n = (ki & 1) ? B1l0 : B1l1;
    short* B2n = (ki & 1) ? B2l0 : B2l1;
    const short* Ac = (ki & 1) ? Al1 : Al0;  // current buffers (parity ki)
    const short* B1c = (ki & 1) ? B1l1 : B1l0;
    const short* B2c = (ki & 1) ? B2l1 : B2l0;

    if (ki < 7) {  // issue next K-step's loads BEFORE compute
#pragma unroll
      for (int i = 0; i < 2; i++) gll(xb + aoff[i] + kc + 64, &An[lb[i]]);
#pragma unroll
      for (int i = 0; i < 2; i++) gll(B1 + bgoff[i] + kc + 64, &B1n[lb[i]]);
      if (routed) {
#pragma unroll
        for (int i = 0; i < 2; i++) gll(B2 + bgoff[i] + kc + 64, &B2n[lb[i]]);
      }
    }

#pragma unroll
    for (int kf = 0; kf < 2; kf++) {
      int kp = (kf * 4 + (lane >> 4)) ^ (lane & 7);
      bf16x8 af[2];
#pragma unroll
      for (int mf = 0; mf < 2; mf++) {
        int row = wm * 32 + mf * 16 + (lane & 15);
        af[mf] = *(const bf16x8*)&Ac[row * 64 + kp * 8];
      }
#pragma unroll
      for (int nf = 0; nf < 2; nf++) {
        int col = wn * 32 + nf * 16 + (lane & 15);
        bf16x8 b1 = *(const bf16x8*)&B1c[col * 64 + kp * 8];
#pragma unroll
        for (int mf = 0; mf < 2; mf++)
          acc[0][mf][nf] = __builtin_amdgcn_mfma_f32_16x16x32_bf16(
              af[mf], b1, acc[0][mf][nf], 0, 0, 0);
        if (routed) {
          bf16x8 b2 = *(const bf16x8*)&B2c[col * 64 + kp * 8];
#pragma unroll
          for (int mf = 0; mf < 2; mf++)
            acc[1][mf][nf] = __builtin_amdgcn_mfma_f32_16x16x32_bf16(
                af[mf], b2, acc[1][mf][nf], 0, 0, 0);
        }
      }
    }
    __syncthreads();  // waves done reading current; prefetch (vmcnt) drained
  }

  // epilogue: activate -> LDS stage (quad-XOR col swizzle) -> coalesced store
  // C/D mapping: col = lane&15, row = quad*4 + reg
  short* S = Al0;  // 64x64 shorts = 8KB; loop-trailing barrier protects reuse
  int quad = lane >> 4;
  short* dst = routed ? h : g;
#pragma unroll
  for (int mf = 0; mf < 2; mf++)
#pragma unroll
    for (int r = 0; r < 4; r++) {
      int lr = wm * 32 + mf * 16 + quad * 4 + r;     // local row 0..63
      int sw = ((lr >> 2) & 3) << 4;
#pragma unroll
      for (int nf = 0; nf < 2; nf++) {
        int lc = wn * 32 + nf * 16 + (lane & 15);
        float a1 = acc[0][mf][nf][r];
        short v;
        if (routed) {
          float a3 = acc[1][mf][nf][r];
          v = f2bf((a1 / (1.f + __expf(-a1))) * a3);
        } else {
          v = f2bf(gelu_exactish(a1));
        }
        S[lr * 64 + ((lc & 48) ^ sw) + (lc & 15)] = v;
      }
    }
  __syncthreads();
  {
    int lr = tid >> 2;                               // 0..63
    int srow = row0 + lr;
    if (srow < cnt) {
      int p = (tid & 3) * 16;                        // 16-col chunk base
      int lcs = p ^ (((lr >> 2) & 3) << 4);
      bf16x8 v0 = *(const bf16x8*)&S[lr * 64 + lcs];
      bf16x8 v1 = *(const bf16x8*)&S[lr * 64 + lcs + 8];
      long ro = (long)(base + srow) * IDIM + n0 + p;
      *(bf16x8*)&dst[ro] = v0;
      *(bf16x8*)&dst[ro + 8] = v1;
    }
  }
}

// ---- stage2: out[perm[rows]] = He@w2^T + Ge@sw2^T, fused, no atomics. -----
// BM=64 BN=32 BK=64 bf16 gll (R5-exact; R8's BK=128 regressed +8.5us —
// barrier count is NOT stage2's limiter). h and g are BOTH in sorted row
// order, so one block sums both GEMMs and stores out exactly once.
// N-split (16 n-tiles) gives 1152 blocks; 12KB LDS -> 8 blocks/CU.
// Bijective XCD chunk-swizzle (1152 = 8 x 144).
__global__ __launch_bounds__(256, 8) void stage2(
    const short* __restrict__ h, const short* __restrict__ g,
    const short* __restrict__ w2b, const short* __restrict__ sw2b,
    float* __restrict__ out, const int* __restrict__ counts,
    const int* __restrict__ offsets, const int* __restrict__ nmeta,
    const int* __restrict__ te, const int* __restrict__ tr,
    const int* __restrict__ perm) {
  __shared__ short Al[64 * 64];   // 8KB
  __shared__ short Bl[32 * 64];   // 4KB
  int lid = blockIdx.x + 16 * blockIdx.y;
  int logical = (lid & 7) * 144 + (lid >> 3);
  int t = logical >> 4;
  int n0 = (logical & 15) * 32;
  if (t >= nmeta[1]) return;
  int e = te[t], row0 = tr[t];
  int cnt = counts[e], base = offsets[e];
  const short* w2e = w2b + (long)e * DIM * IDIM;
  int tid = threadIdx.x, lane = tid & 63, w = tid >> 6;
  int wm = w >> 1, wn = w & 1;

  // A: 64x64 = 512 chunks of 8 bf16, 2 gll/thread
  int aoff[2], lbA[2];
#pragma unroll
  for (int i = 0; i < 2; i++) {
    int c = i * 256 + tid;
    int row = c >> 3, klog = (c & 7) ^ (row & 7);
    int srow = row0 + row;
    int arow = base + ((srow < cnt) ? srow : (cnt - 1));
    aoff[i] = arow * IDIM + klog * 8;
    lbA[i] = (i * 256 + w * 64) * 8;  // wave-uniform base
  }
  // B: 32x64 = 256 chunks, 1 gll/thread
  int brow = tid >> 3, bklog = (tid & 7) ^ (brow & 7);
  int bgoff = (n0 + brow) * IDIM + bklog * 8;
  int lbB = (w * 64) * 8;             // wave-uniform base

  floatx4 acc[2];
  acc[0] = (floatx4)0.f;
  acc[1] = (floatx4)0.f;

#pragma unroll
  for (int ph = 0; ph < 2; ph++) {
    const short* As = ph ? g : h;
    const short* Bs = ph ? sw2b : w2e;
    for (int kc = 0; kc < IDIM; kc += 64) {
#pragma unroll
      for (int i = 0; i < 2; i++) gll(As + aoff[i] + kc, &Al[lbA[i]]);
      gll(Bs + bgoff + kc, &Bl[lbB]);
      __syncthreads();

#pragma unroll
      for (int kf = 0; kf < 2; kf++) {
        int kp = (kf * 4 + (lane >> 4)) ^ (lane & 7);
        int col = wn * 16 + (lane & 15);
        bf16x8 bv = *(const bf16x8*)&Bl[col * 64 + kp * 8];
#pragma unroll
        for (int mf = 0; mf < 2; mf++) {
          int row = wm * 32 + mf * 16 + (lane & 15);
          bf16x8 af = *(const bf16x8*)&Al[row * 64 + kp * 8];
          acc[mf] = __builtin_amdgcn_mfma_f32_16x16x32_bf16(
              af, bv, acc[mf], 0, 0, 0);
        }
      }
      __syncthreads();
    }
  }

  int quad = lane >> 4;
  int colb = n0 + wn * 16 + (lane & 15);
#pragma unroll
  for (int mf = 0; mf < 2; mf++)
#pragma unroll
    for (int r = 0; r < 4; r++) {
      int srow = row0 + wm * 32 + mf * 16 + quad * 4 + r;
      if (srow >= cnt) continue;
      long ro = (long)perm[base + srow] * DIM + colb;
      out[ro] = acc[mf][r];
    }
}

extern "C" void kernel_launch(void* const* d_in, const int* in_sizes, int n_in,
                              void* d_out, int out_size, void* d_ws, size_t ws_size,
                              hipStream_t stream) {
  const float* x = (const float*)d_in[0];
  const float* gate_w = (const float*)d_in[1];
  const float* w1 = (const float*)d_in[2];
  const float* w2 = (const float*)d_in[3];
  const float* w3 = (const float*)d_in[4];
  const float* sw1 = (const float*)d_in[5];
  const float* sw2 = (const float*)d_in[6];
  float* out = (float*)d_out;

  char* ws = (char*)d_ws;
  int* counts = (int*)ws;          // 8
  int* offsets = counts + 8;       // 8
  int* cursors = offsets + 8;      // 8 (unused; layout kept)
  int* nmeta = cursors + 8;        // 8
  int* te1 = nmeta + 8;            // 256 (stride-64 tables, <=135 entries)
  int* tr1 = te1 + 256;            // 256
  int* te2 = tr1 + 256;            // 256
  int* tr2 = te2 + 256;            // 256
  int* expert_id = tr2 + 256;      // 4096
  int* perm = expert_id + N_TOK;   // 4096
  short* xb = (short*)(ws + 65536);        // 4 MB   [N_TOK, DIM] bf16
  short* h = xb + (size_t)N_TOK * DIM;     // 16 MB  [N_TOK, IDIM] sorted rows
  short* g = h + (size_t)N_TOK * IDIM;     // 16 MB  [N_TOK, IDIM] sorted rows
  short* w1b = g + (size_t)N_TOK * IDIM;   // 16 MB  bf16 weights from here
  short* w3b = w1b + (size_t)W1_ELS;       // 16 MB
  short* w2b = w3b + (size_t)W3_ELS;       // 16 MB
  short* sw1b = w2b + (size_t)W2_ELS;      // 2 MB
  short* sw2b = sw1b + (size_t)SW1_ELS;    // 2 MB   total ws ~= 92.4 MB

  gate_conv_kernel<<<GATE_BLOCKS + CONV_BLOCKS, 256, 0, stream>>>(
      x, gate_w, xb, expert_id, w1, w3, w2, sw1, sw2,
      w1b, w3b, w2b, sw1b, sw2b);
  scan_scatter<<<1, 256, 0, stream>>>(expert_id, counts, offsets, cursors, nmeta,
                                      te1, tr1, te2, tr2, perm);
  stage1<<<dim3(IDIM / 64, 136), 256, 0, stream>>>(
      xb, w1b, w3b, sw1b, h, g, counts, offsets, nmeta, te1, tr1, perm);
  stage2<<<dim3(16, 72), 256, 0, stream>>>(
      h, g, w2b, sw2b, out, counts, offsets, nmeta, te2, tr2, perm);
}